// Round 17
// baseline (346.447 us; speedup 1.0000x reference)
//
#include <hip/hip_runtime.h>

#define HID 10
#define STEPS 512

typedef __attribute__((ext_vector_type(2))) float v2f;

// broadcast lane ((lane&0x10)|F) within each 32-lane half -> all lanes of each 16-group
// (one-time use: t=0 peel)
template<int F>
static __device__ __forceinline__ float swz(float v) {
    return __int_as_float(__builtin_amdgcn_ds_swizzle(__float_as_int(v), (F << 5) | 0x10));
}

// DPP row_ror:J within 16-lane rows (VALU pipe, ~4cy). Self-calibrated via the
// irot probe (R2/R3 verified correct end-to-end), so direction is irrelevant.
template<int J>
static __device__ __forceinline__ float frot(float v) {
    return __int_as_float(__builtin_amdgcn_update_dpp(
        0, __float_as_int(v), 0x120 + J, 0xF, 0xF, true));
}
template<int J>
static __device__ __forceinline__ int irot(int v) {
    return __builtin_amdgcn_update_dpp(0, v, 0x120 + J, 0xF, 0xF, true);
}

// Lane-parallel fused GRU decoder, 1 feature per lane, 4 batches per wave.
// v17 = v16 (147.5us) with the LDS gather replaced by 15 DPP row-rotations:
//   the loop contains ZERO DS ops — the ~140cy write->read roundtrip (v16's
//   remaining exposed stall) is replaced by ~4cy rotation latency.
//   Dots: 8 pk-layers x 5 families over GENUINE pairs {rot2m(h), rot2m+1(h)}
//   (no splat-movs — R2/R3's DPP regression is attributed to splatted pairs
//   {ha,ha} + unpacked o + 2-rcp tail + residual spills; all absent here).
//   6 of 16 terms per lane are zero-weighted (structural in a 16-ring),
//   weights self-calibrated by the irot probe. Kernel becomes issue-bound,
//   where 2-wave TLP is reliable (this session: 2-wave latency-hiding of
//   trans bubbles works; latency-bound LDS stalls were never fully hidden).
__attribute__((amdgpu_waves_per_eu(2, 2)))
__global__ __launch_bounds__(64) void gru_decoder_kernel(
    const float* __restrict__ hidden, const float* __restrict__ w_ih,
    const float* __restrict__ w_hh, const float* __restrict__ b_ih,
    const float* __restrict__ b_hh, const float* __restrict__ l1_w,
    const float* __restrict__ l1_b, const float* __restrict__ l2_w,
    const float* __restrict__ l2_b, float* __restrict__ out)
{
    __shared__ float sWx[640];   // l2_w @ l1_w (64x10)
    __shared__ float sbx[64];    // l2_w @ l1_b + l2_b
    __shared__ float sWgi[300];  // w_ih @ Wx (30x10)
    __shared__ float sbgi[30];   // b_ih + w_ih @ bx
    __shared__ float sWhh[300];  // w_hh copy (t=0 peel + weight build)

    const int lane = threadIdx.x;
    const int f    = lane & 15;
    const int g    = lane >> 4;
    const int b    = blockIdx.x * 4 + g;
    const bool ok  = (f < HID);
    const int fi   = ok ? f : 0;          // clamped index for safe reads

    // ---- preamble: fused weights (fp32, cooperative) ----
    for (int e = lane; e < 640; e += 64) {
        int i = e / 10, j = e - i * 10;
        float acc = 0.f;
        #pragma unroll
        for (int k = 0; k < 10; ++k) acc += l2_w[i * 10 + k] * l1_w[k * 10 + j];
        sWx[e] = acc;
    }
    {
        float acc = l2_b[lane];
        #pragma unroll
        for (int k = 0; k < 10; ++k) acc += l2_w[lane * 10 + k] * l1_b[k];
        sbx[lane] = acc;
    }
    for (int e = lane; e < 300; e += 64) sWhh[e] = w_hh[e];
    __syncthreads();
    for (int e = lane; e < 300; e += 64) {
        int m = e / 10, j = e - m * 10;
        float acc = 0.f;
        for (int k = 0; k < 64; ++k) acc += w_ih[m * 64 + k] * sWx[k * 10 + j];
        sWgi[e] = acc;
    }
    if (lane < 30) {
        float acc = b_ih[lane];
        for (int k = 0; k < 64; ++k) acc += w_ih[lane * 64 + k] * sbx[k];
        sbgi[lane] = acc;
    }
    __syncthreads();

    const float LOG2E = 1.4426950408889634f;
    const float S2    = 2.f * LOG2E;

    // ---- self-calibrated rotation source features (16-ring) ----
    const int s0  = f;
    const int s1  = irot<1>(f);   const int s2  = irot<2>(f);
    const int s3  = irot<3>(f);   const int s4  = irot<4>(f);
    const int s5  = irot<5>(f);   const int s6  = irot<6>(f);
    const int s7  = irot<7>(f);   const int s8  = irot<8>(f);
    const int s9  = irot<9>(f);   const int s10 = irot<10>(f);
    const int s11 = irot<11>(f);  const int s12 = irot<12>(f);
    const int s13 = irot<13>(f);  const int s14 = irot<14>(f);
    const int s15 = irot<15>(f);

    // ---- per-lane weight getters (0 for invalid source or padded lane) ----
    auto WGR = [&](int s)->float { int c = (s < 10) ? s : 0;
        return (ok && s < 10) ? -(sWgi[fi * 10 + c] + sWhh[fi * 10 + c]) * LOG2E : 0.f; };
    auto WGZ = [&](int s)->float { int c = (s < 10) ? s : 0;
        return (ok && s < 10) ? -(sWgi[(10 + fi) * 10 + c] + sWhh[(10 + fi) * 10 + c]) * LOG2E : 0.f; };
    auto WGI = [&](int s)->float { int c = (s < 10) ? s : 0;
        return (ok && s < 10) ? sWgi[(20 + fi) * 10 + c] * S2 : 0.f; };
    auto WGH = [&](int s)->float { int c = (s < 10) ? s : 0;
        return (ok && s < 10) ? sWhh[(20 + fi) * 10 + c] * S2 : 0.f; };
    auto WGO = [&](int s)->float { int c = (s < 10) ? s : 0;
        return (ok && s < 10) ? l1_w[fi * 10 + c] : 0.f; };

    // ---- paired weight tables, NAMED values (8 pairs x 5 families) ----
    #define MKP(m, sa, sb)                                                       \
        const v2f wrP##m = {WGR(sa), WGR(sb)};                                   \
        const v2f wzP##m = {WGZ(sa), WGZ(sb)};                                   \
        const v2f wiP##m = {WGI(sa), WGI(sb)};                                   \
        const v2f whP##m = {WGH(sa), WGH(sb)};                                   \
        const v2f woP##m = {WGO(sa), WGO(sb)};
    MKP(0, s0,  s1)  MKP(1, s2,  s3)  MKP(2, s4,  s5)  MKP(3, s6,  s7)
    MKP(4, s8,  s9)  MKP(5, s10, s11) MKP(6, s12, s13) MKP(7, s14, s15)
    #undef MKP

    const float br = ok ? -(sbgi[fi] + b_hh[fi]) * LOG2E : 0.f;
    const float bz = ok ? -(sbgi[10 + fi] + b_hh[10 + fi]) * LOG2E : 0.f;
    const float bi = ok ? sbgi[20 + fi] * S2 : 0.f;
    const float bh = ok ? b_hh[20 + fi] * S2 : 0.f;
    const float bo = ok ? l1_b[fi] : 0.f;
    const v2f BR2 = {br, 0.f}, BZ2 = {bz, 0.f}, BI2 = {bi, 0.f},
              BH2 = {bh, 0.f}, BO2 = {bo, 0.f};
    // t=0 peel biases (gi = b_ih only)
    const float br0_ = ok ? -(b_ih[fi] + b_hh[fi]) * LOG2E : 0.f;
    const float bz0_ = ok ? -(b_ih[10 + fi] + b_hh[10 + fi]) * LOG2E : 0.f;
    const float bni0 = ok ? b_ih[20 + fi] * S2 : 0.f;

    // ---- initial h (one feature per lane; f>=10 stays exactly 0) ----
    float h = ok ? hidden[(size_t)b * HID + f] : 0.f;

    float* pb = out + (size_t)b * (STEPS * HID) + (size_t)(STEPS - 1) * HID + f;

    // ---- t = 0 peeled: gi = b_ih only (x_0 = 0); raw w_hh dots from LDS ----
    // Produces h1. o_0 = l1(h1) is stored by the first loop iteration.
    {
        float ha[10];
        ha[0] = swz<0>(h); ha[1] = swz<1>(h); ha[2] = swz<2>(h);
        ha[3] = swz<3>(h); ha[4] = swz<4>(h); ha[5] = swz<5>(h);
        ha[6] = swz<6>(h); ha[7] = swz<7>(h); ha[8] = swz<8>(h);
        ha[9] = swz<9>(h);
        float pr = 0.f, pz = 0.f, ph = 0.f;
        #pragma unroll
        for (int k = 0; k < 10; ++k) {
            pr += sWhh[fi * 10 + k] * ha[k];
            pz += sWhh[(10 + fi) * 10 + k] * ha[k];
            ph += sWhh[(20 + fi) * 10 + k] * ha[k];
        }
        float vr = br0_ - pr * LOG2E;
        float vz = bz0_ - pz * LOG2E;
        float r = __builtin_amdgcn_rcpf(1.f + __builtin_amdgcn_exp2f(vr));
        float z = __builtin_amdgcn_rcpf(1.f + __builtin_amdgcn_exp2f(vz));
        float y = bni0 + r * (ph * S2 + bh);
        float n = 1.f - 2.f * __builtin_amdgcn_rcpf(1.f + __builtin_amdgcn_exp2f(y));
        h = ok ? (n + z * (h - n)) : 0.f;
    }

    // ---- t = 1 .. 511 : DPP gather (no DS), 8 pk-layers x 5 families ----
    #pragma unroll 1
    for (int t = 1; t < STEPS; ++t) {
        float rh1  = frot<1>(h);   float rh2  = frot<2>(h);
        float rh3  = frot<3>(h);   float rh4  = frot<4>(h);
        float rh5  = frot<5>(h);   float rh6  = frot<6>(h);
        float rh7  = frot<7>(h);   float rh8  = frot<8>(h);
        float rh9  = frot<9>(h);   float rh10 = frot<10>(h);
        float rh11 = frot<11>(h);  float rh12 = frot<12>(h);
        float rh13 = frot<13>(h);  float rh14 = frot<14>(h);
        float rh15 = frot<15>(h);
        v2f hp0 = {h,    rh1};   v2f hp1 = {rh2,  rh3};
        v2f hp2 = {rh4,  rh5};   v2f hp3 = {rh6,  rh7};
        v2f hp4 = {rh8,  rh9};   v2f hp5 = {rh10, rh11};
        v2f hp6 = {rh12, rh13};  v2f hp7 = {rh14, rh15};

        v2f ar = wrP0 * hp0 + BR2;
        v2f az = wzP0 * hp0 + BZ2;
        v2f ai = wiP0 * hp0 + BI2;
        v2f ah = whP0 * hp0 + BH2;
        v2f ao = woP0 * hp0 + BO2;
        ar += wrP1 * hp1; az += wzP1 * hp1; ai += wiP1 * hp1;
        ah += whP1 * hp1; ao += woP1 * hp1;
        ar += wrP2 * hp2; az += wzP2 * hp2; ai += wiP2 * hp2;
        ah += whP2 * hp2; ao += woP2 * hp2;
        ar += wrP3 * hp3; az += wzP3 * hp3; ai += wiP3 * hp3;
        ah += whP3 * hp3; ao += woP3 * hp3;
        ar += wrP4 * hp4; az += wzP4 * hp4; ai += wiP4 * hp4;
        ah += whP4 * hp4; ao += woP4 * hp4;
        ar += wrP5 * hp5; az += wzP5 * hp5; ai += wiP5 * hp5;
        ah += whP5 * hp5; ao += woP5 * hp5;
        ar += wrP6 * hp6; az += wzP6 * hp6; ai += wiP6 * hp6;
        ah += whP6 * hp6; ao += woP6 * hp6;
        ar += wrP7 * hp7; az += wzP7 * hp7; ai += wiP7 * hp7;
        ah += whP7 * hp7; ao += woP7 * hp7;

        float arx = ar.x + ar.y;
        float azx = az.x + az.y;
        float aix = ai.x + ai.y;
        float ahx = ah.x + ah.y;
        float o   = ao.x + ao.y;          // = l1(h_t) = o_{t-1}

        // r-gate, then fused z/n update with a single rcp:
        //   h' = (ez*(en-1) + h*(en+1)) / ((en+1)*(1+ez))
        float er = __builtin_amdgcn_exp2f(arx);
        float rr = __builtin_amdgcn_rcpf(1.f + er);
        float ez = __builtin_amdgcn_exp2f(azx);
        float y  = __builtin_fmaf(rr, ahx, aix);
        float en = __builtin_amdgcn_exp2f(y);
        float pp = en * ez;
        float u  = pp + (h - ez);
        float num = __builtin_fmaf(h, en, u);
        float den = (pp + (en + ez)) + 1.f;
        h = num * __builtin_amdgcn_rcpf(den);   // padded lanes: h stays 0

        if (ok) pb[0] = o;                 // store o_{t-1} (position STEPS-t)
        pb -= HID;
    }

    // ---- epilogue: o_511 = l1(h_512) at position 0 ----
    {
        float rh1  = frot<1>(h);   float rh2  = frot<2>(h);
        float rh3  = frot<3>(h);   float rh4  = frot<4>(h);
        float rh5  = frot<5>(h);   float rh6  = frot<6>(h);
        float rh7  = frot<7>(h);   float rh8  = frot<8>(h);
        float rh9  = frot<9>(h);   float rh10 = frot<10>(h);
        float rh11 = frot<11>(h);  float rh12 = frot<12>(h);
        float rh13 = frot<13>(h);  float rh14 = frot<14>(h);
        float rh15 = frot<15>(h);
        v2f ao = woP0 * v2f{h, rh1} + BO2;
        ao += woP1 * v2f{rh2,  rh3};
        ao += woP2 * v2f{rh4,  rh5};
        ao += woP3 * v2f{rh6,  rh7};
        ao += woP4 * v2f{rh8,  rh9};
        ao += woP5 * v2f{rh10, rh11};
        ao += woP6 * v2f{rh12, rh13};
        ao += woP7 * v2f{rh14, rh15};
        if (ok) pb[0] = ao.x + ao.y;
    }
}

extern "C" void kernel_launch(void* const* d_in, const int* in_sizes, int n_in,
                              void* d_out, int out_size, void* d_ws, size_t ws_size,
                              hipStream_t stream) {
    (void)in_sizes; (void)n_in; (void)d_ws; (void)ws_size; (void)out_size;
    dim3 grid(2048), block(64);   // 4 batches/wave, 2048 waves -> 2 waves per SIMD
    gru_decoder_kernel<<<grid, block, 0, stream>>>(
        (const float*)d_in[0], (const float*)d_in[1], (const float*)d_in[2],
        (const float*)d_in[3], (const float*)d_in[4], (const float*)d_in[5],
        (const float*)d_in[6], (const float*)d_in[7], (const float*)d_in[8],
        (float*)d_out);
}

// Round 18
// 281.459 us; speedup vs baseline: 1.2309x; 1.2309x over previous
//
#include <hip/hip_runtime.h>

#define HID 10
#define STEPS 512

typedef __attribute__((ext_vector_type(2))) float v2f;
typedef __attribute__((ext_vector_type(4))) float v4f;

// broadcast lane ((lane&0x10)|F) within each 32-lane half -> all lanes of each 16-group
// (one-time use: t=0 peel + epilogue)
template<int F>
static __device__ __forceinline__ float swz(float v) {
    return __int_as_float(__builtin_amdgcn_ds_swizzle(__float_as_int(v), (F << 5) | 0x10));
}

// Lane-parallel fused GRU decoder, 1 feature per lane, 4 batches per wave.
//   batch = blockIdx*4 + (lane>>4); f = lane&15 (f>=10: zero-padded, stores masked)
// v18 = v16 (147.5us best) + PERSISTENT priority asymmetry.
//   v16 counters: period 691 cyc/SIMD-step, issue 434 (VALUBusy 62.9% = 434/691
//   exactly): the two co-resident waves stall SIMULTANEOUSLY for 257 cyc/step
//   (lockstep convoy). One-time phase offsets dissolve under fair round-robin
//   (R7/R10 null). s_setprio keyed on the physical wave slot is PERSISTENT:
//   the arbiter always favors the high wave when both are ready, forcing the
//   low wave to issue only inside the high wave's stall windows — the phase
//   split is re-imposed every cycle instead of decaying. Ideal period ~480.
//   DPP gather falsified twice (R2/R3: 228us, R17: 217us — pair-packing movs
//   + 15 dpp movs cost more issue than the DS roundtrip saves). DS gather +
//   o-dot-in-window (v16) is the right structure.
__attribute__((amdgpu_waves_per_eu(2, 2)))
__global__ __launch_bounds__(64) void gru_decoder_kernel(
    const float* __restrict__ hidden, const float* __restrict__ w_ih,
    const float* __restrict__ w_hh, const float* __restrict__ b_ih,
    const float* __restrict__ b_hh, const float* __restrict__ l1_w,
    const float* __restrict__ l1_b, const float* __restrict__ l2_w,
    const float* __restrict__ l2_b, float* __restrict__ out)
{
    __shared__ float sWx[640];   // l2_w @ l1_w (64x10)
    __shared__ float sbx[64];    // l2_w @ l1_b + l2_b
    __shared__ float sWgi[300];  // w_ih @ Wx (30x10)
    __shared__ float sbgi[30];   // b_ih + w_ih @ bx
    __shared__ float sWhh[300];  // w_hh copy (t=0 peel + weight build)
    __shared__ float sH[64];     // 4 groups x 16-float rows (gather staging)

    const int lane = threadIdx.x;
    const int f    = lane & 15;
    const int g    = lane >> 4;
    const int b    = blockIdx.x * 4 + g;
    const bool ok  = (f < HID);
    const int fi   = ok ? f : 0;          // clamped index for safe reads

    // ---- preamble: fused weights (fp32, cooperative) ----
    for (int e = lane; e < 640; e += 64) {
        int i = e / 10, j = e - i * 10;
        float acc = 0.f;
        #pragma unroll
        for (int k = 0; k < 10; ++k) acc += l2_w[i * 10 + k] * l1_w[k * 10 + j];
        sWx[e] = acc;
    }
    {
        float acc = l2_b[lane];
        #pragma unroll
        for (int k = 0; k < 10; ++k) acc += l2_w[lane * 10 + k] * l1_b[k];
        sbx[lane] = acc;
    }
    for (int e = lane; e < 300; e += 64) sWhh[e] = w_hh[e];
    __syncthreads();
    for (int e = lane; e < 300; e += 64) {
        int m = e / 10, j = e - m * 10;
        float acc = 0.f;
        for (int k = 0; k < 64; ++k) acc += w_ih[m * 64 + k] * sWx[k * 10 + j];
        sWgi[e] = acc;
    }
    if (lane < 30) {
        float acc = b_ih[lane];
        for (int k = 0; k < 64; ++k) acc += w_ih[lane * 64 + k] * sbx[k];
        sbgi[lane] = acc;
    }
    __syncthreads();

    const float LOG2E = 1.4426950408889634f;
    const float S2    = 2.f * LOG2E;

    // ---- per-lane weights (feature fi), packed across k, NAMED values ----
    #define MKW(k2)                                                              \
        const int k0_##k2 = 2 * (k2), k1_##k2 = 2 * (k2) + 1;                    \
        const v2f wr##k2 = ok ? v2f{                                             \
            -(sWgi[fi * 10 + k0_##k2] + sWhh[fi * 10 + k0_##k2]) * LOG2E,        \
            -(sWgi[fi * 10 + k1_##k2] + sWhh[fi * 10 + k1_##k2]) * LOG2E}        \
            : v2f{0.f, 0.f};                                                     \
        const v2f wz##k2 = ok ? v2f{                                             \
            -(sWgi[(10 + fi) * 10 + k0_##k2] + sWhh[(10 + fi) * 10 + k0_##k2]) * LOG2E, \
            -(sWgi[(10 + fi) * 10 + k1_##k2] + sWhh[(10 + fi) * 10 + k1_##k2]) * LOG2E} \
            : v2f{0.f, 0.f};                                                     \
        const v2f wi##k2 = ok ? v2f{                                             \
            sWgi[(20 + fi) * 10 + k0_##k2] * S2,                                 \
            sWgi[(20 + fi) * 10 + k1_##k2] * S2} : v2f{0.f, 0.f};                \
        const v2f wh##k2 = ok ? v2f{                                             \
            sWhh[(20 + fi) * 10 + k0_##k2] * S2,                                 \
            sWhh[(20 + fi) * 10 + k1_##k2] * S2} : v2f{0.f, 0.f};                \
        const v2f wo##k2 = ok ? v2f{                                             \
            l1_w[fi * 10 + k0_##k2], l1_w[fi * 10 + k1_##k2]} : v2f{0.f, 0.f};
    MKW(0) MKW(1) MKW(2) MKW(3) MKW(4)
    #undef MKW

    const float br = ok ? -(sbgi[fi] + b_hh[fi]) * LOG2E : 0.f;
    const float bz = ok ? -(sbgi[10 + fi] + b_hh[10 + fi]) * LOG2E : 0.f;
    const float bi = ok ? sbgi[20 + fi] * S2 : 0.f;
    const float bh = ok ? b_hh[20 + fi] * S2 : 0.f;
    const float bo = ok ? l1_b[fi] : 0.f;
    const v2f BR2 = {br, 0.f}, BZ2 = {bz, 0.f}, BI2 = {bi, 0.f},
              BH2 = {bh, 0.f}, BO2 = {bo, 0.f};
    // t=0 peel biases (gi = b_ih only)
    const float br0_ = ok ? -(b_ih[fi] + b_hh[fi]) * LOG2E : 0.f;
    const float bz0_ = ok ? -(b_ih[10 + fi] + b_hh[10 + fi]) * LOG2E : 0.f;
    const float bni0 = ok ? b_ih[20 + fi] * S2 : 0.f;

    // ---- initial h (one feature per lane; f>=10 stays exactly 0) ----
    float h = ok ? hidden[(size_t)b * HID + f] : 0.f;

    float* pb = out + (size_t)b * (STEPS * HID) + (size_t)(STEPS - 1) * HID + f;
    float* sHrow = &sH[g * 16];

    // ---- t = 0 peeled: gi = b_ih only (x_0 = 0); raw w_hh dots from LDS ----
    // Produces h1. o_0 = l1(h1) is stored by the first loop iteration.
    {
        float ha[10];
        ha[0] = swz<0>(h); ha[1] = swz<1>(h); ha[2] = swz<2>(h);
        ha[3] = swz<3>(h); ha[4] = swz<4>(h); ha[5] = swz<5>(h);
        ha[6] = swz<6>(h); ha[7] = swz<7>(h); ha[8] = swz<8>(h);
        ha[9] = swz<9>(h);
        float pr = 0.f, pz = 0.f, ph = 0.f;
        #pragma unroll
        for (int k = 0; k < 10; ++k) {
            pr += sWhh[fi * 10 + k] * ha[k];
            pz += sWhh[(10 + fi) * 10 + k] * ha[k];
            ph += sWhh[(20 + fi) * 10 + k] * ha[k];
        }
        float vr = br0_ - pr * LOG2E;
        float vz = bz0_ - pz * LOG2E;
        float r = __builtin_amdgcn_rcpf(1.f + __builtin_amdgcn_exp2f(vr));
        float z = __builtin_amdgcn_rcpf(1.f + __builtin_amdgcn_exp2f(vz));
        float y = bni0 + r * (ph * S2 + bh);
        float n = 1.f - 2.f * __builtin_amdgcn_rcpf(1.f + __builtin_amdgcn_exp2f(y));
        h = ok ? (n + z * (h - n)) : 0.f;
    }

    // ---- persistent priority asymmetry keyed on physical wave slot ----
    // HW_REG_HW_ID (id=4), offset 0, size 4 -> WAVE_ID[3:0]; imm = (3<<11)|4.
    // Distinct co-resident slots -> distinct priorities: the arbiter favors the
    // high wave whenever both are ready, pinning the waves in anti-phase.
    {
        int p = __builtin_amdgcn_s_getreg(0x1804) & 3;
        if (p == 1)      __builtin_amdgcn_s_setprio(1);
        else if (p == 2) __builtin_amdgcn_s_setprio(2);
        else if (p == 3) __builtin_amdgcn_s_setprio(3);
    }

    // ---- prologue: stage h_1 and issue the first gather ----
    sHrow[f] = h;
    __builtin_amdgcn_wave_barrier();
    __builtin_amdgcn_sched_barrier(0);
    v4f p0 = *(const v4f*)(sHrow);
    v4f p1 = *(const v4f*)(sHrow + 4);
    v2f p2 = *(const v2f*)(sHrow + 8);
    v4f r0, r1; v2f r2;

    // One iteration: gates from (a0,a1,a2) -> new h; write h; issue reads into
    // (n0,n1,n2); THEN o-dot from the old (a0,a1,a2) + store — the o-dot and
    // store fill the LDS write->read roundtrip window.
    #define STEP(a0, a1, a2, n0, n1, n2)                                        \
    {                                                                           \
        v2f h2_0 = __builtin_shufflevector(a0, a0, 0, 1);                       \
        v2f h2_1 = __builtin_shufflevector(a0, a0, 2, 3);                       \
        v2f h2_2 = __builtin_shufflevector(a1, a1, 0, 1);                       \
        v2f h2_3 = __builtin_shufflevector(a1, a1, 2, 3);                       \
        v2f h2_4 = a2;                                                          \
        v2f ar = wr0 * h2_0 + BR2;                                              \
        v2f az = wz0 * h2_0 + BZ2;                                              \
        v2f ai = wi0 * h2_0 + BI2;                                              \
        v2f ah = wh0 * h2_0 + BH2;                                              \
        ar += wr1 * h2_1; az += wz1 * h2_1; ai += wi1 * h2_1; ah += wh1 * h2_1; \
        ar += wr2 * h2_2; az += wz2 * h2_2; ai += wi2 * h2_2; ah += wh2 * h2_2; \
        ar += wr3 * h2_3; az += wz3 * h2_3; ai += wi3 * h2_3; ah += wh3 * h2_3; \
        ar += wr4 * h2_4; az += wz4 * h2_4; ai += wi4 * h2_4; ah += wh4 * h2_4; \
        float arx = ar.x + ar.y;                                                \
        float azx = az.x + az.y;                                                \
        float aix = ai.x + ai.y;                                                \
        float ahx = ah.x + ah.y;                                                \
        float er = __builtin_amdgcn_exp2f(arx);                                 \
        float rr = __builtin_amdgcn_rcpf(1.f + er);                             \
        float ez = __builtin_amdgcn_exp2f(azx);                                 \
        float y  = __builtin_fmaf(rr, ahx, aix);                                \
        float en = __builtin_amdgcn_exp2f(y);                                   \
        float pp = en * ez;                                                     \
        float u  = pp + (h - ez);                                               \
        float num = __builtin_fmaf(h, en, u);                                   \
        float den = (pp + (en + ez)) + 1.f;                                     \
        h = num * __builtin_amdgcn_rcpf(den);   /* padded lanes: h stays 0 */   \
        sHrow[f] = h;                                                           \
        __builtin_amdgcn_wave_barrier();                                        \
        __builtin_amdgcn_sched_barrier(0);                                      \
        n0 = *(const v4f*)(sHrow);                                              \
        n1 = *(const v4f*)(sHrow + 4);                                          \
        n2 = *(const v2f*)(sHrow + 8);                                          \
        /* o-dot from OLD gather regs: fills the roundtrip window */            \
        v2f ao = wo0 * h2_0 + BO2;                                              \
        ao += wo1 * h2_1;                                                       \
        ao += wo2 * h2_2;                                                       \
        ao += wo3 * h2_3;                                                       \
        ao += wo4 * h2_4;                                                       \
        float o = ao.x + ao.y;            /* = l1(h_t) = o_{t-1} */             \
        if (ok) pb[0] = o;                                                      \
        pb -= HID;                                                              \
    }

    // ---- t = 1 .. 510 (255 ping-pong pairs), then t = 511 peeled ----
    #pragma unroll 1
    for (int t = 1; t + 1 < STEPS; t += 2) {
        STEP(p0, p1, p2, r0, r1, r2);
        STEP(r0, r1, r2, p0, p1, p2);
    }
    STEP(p0, p1, p2, r0, r1, r2);       // t = 511; r now holds gather of h_512
    #undef STEP

    // ---- epilogue: o_511 = l1(h_512) at position 0 ----
    {
        v2f ao = wo0 * __builtin_shufflevector(r0, r0, 0, 1) + BO2;
        ao += wo1 * __builtin_shufflevector(r0, r0, 2, 3);
        ao += wo2 * __builtin_shufflevector(r1, r1, 0, 1);
        ao += wo3 * __builtin_shufflevector(r1, r1, 2, 3);
        ao += wo4 * r2;
        if (ok) pb[0] = ao.x + ao.y;
    }
}

extern "C" void kernel_launch(void* const* d_in, const int* in_sizes, int n_in,
                              void* d_out, int out_size, void* d_ws, size_t ws_size,
                              hipStream_t stream) {
    (void)in_sizes; (void)n_in; (void)d_ws; (void)ws_size; (void)out_size;
    dim3 grid(2048), block(64);   // 4 batches/wave, 2048 waves -> 2 waves per SIMD
    gru_decoder_kernel<<<grid, block, 0, stream>>>(
        (const float*)d_in[0], (const float*)d_in[1], (const float*)d_in[2],
        (const float*)d_in[3], (const float*)d_in[4], (const float*)d_in[5],
        (const float*)d_in[6], (const float*)d_in[7], (const float*)d_in[8],
        (float*)d_out);
}

// Round 19
// 279.647 us; speedup vs baseline: 1.2389x; 1.0065x over previous
//
#include <hip/hip_runtime.h>

#define HID 10
#define STEPS 512

typedef __attribute__((ext_vector_type(2))) float v2f;
typedef __attribute__((ext_vector_type(4))) float v4f;

// broadcast lane ((lane&0x10)|F) within each 32-lane half -> all lanes of each 16-group
// (one-time use: t=0 peel + epilogue)
template<int F>
static __device__ __forceinline__ float swz(float v) {
    return __int_as_float(__builtin_amdgcn_ds_swizzle(__float_as_int(v), (F << 5) | 0x10));
}

// Lane-parallel fused GRU decoder, 1 feature per lane, 4 batches per wave.
//   batch = blockIdx*4 + (lane>>4); f = lane&15 (f>=10: zero-padded, stores masked)
// v19 = v18 (145.6us best) with the in-loop fences REMOVED.
//   The wave_barrier+sched_barrier(0) between LDS write and reads (inherited
//   from v5) is redundant: write sHrow[f] and reads *(v4f*)sHrow alias through
//   the same base -> compiler must order them; DS is in-order per wave in HW.
//   sched_barrier(0) actively FORBIDS the scheduler from moving independent
//   work (o-dot, store addressing, loop overhead) into the write->read shadow
//   and from hoisting read-issue early. v16 filled the window manually with
//   the o-dot (+7%); this frees the scheduler to fill it with everything else.
//   Ledger: period 682 cyc/SIMD-step = issue 434 + stall 248; per-wave cycle
//   ~280 (roundtrip 140 + dots 40 + trans tail 90). Falsified with counters:
//   1-wave/SIMD x3, in-wave dual-stream x3, DPP gather x2, pair-pack, 8-lane,
//   sleep-stagger x2. setprio asymmetry kept (+1.3% real).
__attribute__((amdgpu_waves_per_eu(2, 2)))
__global__ __launch_bounds__(64) void gru_decoder_kernel(
    const float* __restrict__ hidden, const float* __restrict__ w_ih,
    const float* __restrict__ w_hh, const float* __restrict__ b_ih,
    const float* __restrict__ b_hh, const float* __restrict__ l1_w,
    const float* __restrict__ l1_b, const float* __restrict__ l2_w,
    const float* __restrict__ l2_b, float* __restrict__ out)
{
    __shared__ float sWx[640];   // l2_w @ l1_w (64x10)
    __shared__ float sbx[64];    // l2_w @ l1_b + l2_b
    __shared__ float sWgi[300];  // w_ih @ Wx (30x10)
    __shared__ float sbgi[30];   // b_ih + w_ih @ bx
    __shared__ float sWhh[300];  // w_hh copy (t=0 peel + weight build)
    __shared__ float sH[64];     // 4 groups x 16-float rows (gather staging)

    const int lane = threadIdx.x;
    const int f    = lane & 15;
    const int g    = lane >> 4;
    const int b    = blockIdx.x * 4 + g;
    const bool ok  = (f < HID);
    const int fi   = ok ? f : 0;          // clamped index for safe reads

    // ---- preamble: fused weights (fp32, cooperative) ----
    for (int e = lane; e < 640; e += 64) {
        int i = e / 10, j = e - i * 10;
        float acc = 0.f;
        #pragma unroll
        for (int k = 0; k < 10; ++k) acc += l2_w[i * 10 + k] * l1_w[k * 10 + j];
        sWx[e] = acc;
    }
    {
        float acc = l2_b[lane];
        #pragma unroll
        for (int k = 0; k < 10; ++k) acc += l2_w[lane * 10 + k] * l1_b[k];
        sbx[lane] = acc;
    }
    for (int e = lane; e < 300; e += 64) sWhh[e] = w_hh[e];
    __syncthreads();
    for (int e = lane; e < 300; e += 64) {
        int m = e / 10, j = e - m * 10;
        float acc = 0.f;
        for (int k = 0; k < 64; ++k) acc += w_ih[m * 64 + k] * sWx[k * 10 + j];
        sWgi[e] = acc;
    }
    if (lane < 30) {
        float acc = b_ih[lane];
        for (int k = 0; k < 64; ++k) acc += w_ih[lane * 64 + k] * sbx[k];
        sbgi[lane] = acc;
    }
    __syncthreads();

    const float LOG2E = 1.4426950408889634f;
    const float S2    = 2.f * LOG2E;

    // ---- per-lane weights (feature fi), packed across k, NAMED values ----
    #define MKW(k2)                                                              \
        const int k0_##k2 = 2 * (k2), k1_##k2 = 2 * (k2) + 1;                    \
        const v2f wr##k2 = ok ? v2f{                                             \
            -(sWgi[fi * 10 + k0_##k2] + sWhh[fi * 10 + k0_##k2]) * LOG2E,        \
            -(sWgi[fi * 10 + k1_##k2] + sWhh[fi * 10 + k1_##k2]) * LOG2E}        \
            : v2f{0.f, 0.f};                                                     \
        const v2f wz##k2 = ok ? v2f{                                             \
            -(sWgi[(10 + fi) * 10 + k0_##k2] + sWhh[(10 + fi) * 10 + k0_##k2]) * LOG2E, \
            -(sWgi[(10 + fi) * 10 + k1_##k2] + sWhh[(10 + fi) * 10 + k1_##k2]) * LOG2E} \
            : v2f{0.f, 0.f};                                                     \
        const v2f wi##k2 = ok ? v2f{                                             \
            sWgi[(20 + fi) * 10 + k0_##k2] * S2,                                 \
            sWgi[(20 + fi) * 10 + k1_##k2] * S2} : v2f{0.f, 0.f};                \
        const v2f wh##k2 = ok ? v2f{                                             \
            sWhh[(20 + fi) * 10 + k0_##k2] * S2,                                 \
            sWhh[(20 + fi) * 10 + k1_##k2] * S2} : v2f{0.f, 0.f};                \
        const v2f wo##k2 = ok ? v2f{                                             \
            l1_w[fi * 10 + k0_##k2], l1_w[fi * 10 + k1_##k2]} : v2f{0.f, 0.f};
    MKW(0) MKW(1) MKW(2) MKW(3) MKW(4)
    #undef MKW

    const float br = ok ? -(sbgi[fi] + b_hh[fi]) * LOG2E : 0.f;
    const float bz = ok ? -(sbgi[10 + fi] + b_hh[10 + fi]) * LOG2E : 0.f;
    const float bi = ok ? sbgi[20 + fi] * S2 : 0.f;
    const float bh = ok ? b_hh[20 + fi] * S2 : 0.f;
    const float bo = ok ? l1_b[fi] : 0.f;
    const v2f BR2 = {br, 0.f}, BZ2 = {bz, 0.f}, BI2 = {bi, 0.f},
              BH2 = {bh, 0.f}, BO2 = {bo, 0.f};
    // t=0 peel biases (gi = b_ih only)
    const float br0_ = ok ? -(b_ih[fi] + b_hh[fi]) * LOG2E : 0.f;
    const float bz0_ = ok ? -(b_ih[10 + fi] + b_hh[10 + fi]) * LOG2E : 0.f;
    const float bni0 = ok ? b_ih[20 + fi] * S2 : 0.f;

    // ---- initial h (one feature per lane; f>=10 stays exactly 0) ----
    float h = ok ? hidden[(size_t)b * HID + f] : 0.f;

    float* pb = out + (size_t)b * (STEPS * HID) + (size_t)(STEPS - 1) * HID + f;
    float* sHrow = &sH[g * 16];

    // ---- t = 0 peeled: gi = b_ih only (x_0 = 0); raw w_hh dots from LDS ----
    // Produces h1. o_0 = l1(h1) is stored by the first loop iteration.
    {
        float ha[10];
        ha[0] = swz<0>(h); ha[1] = swz<1>(h); ha[2] = swz<2>(h);
        ha[3] = swz<3>(h); ha[4] = swz<4>(h); ha[5] = swz<5>(h);
        ha[6] = swz<6>(h); ha[7] = swz<7>(h); ha[8] = swz<8>(h);
        ha[9] = swz<9>(h);
        float pr = 0.f, pz = 0.f, ph = 0.f;
        #pragma unroll
        for (int k = 0; k < 10; ++k) {
            pr += sWhh[fi * 10 + k] * ha[k];
            pz += sWhh[(10 + fi) * 10 + k] * ha[k];
            ph += sWhh[(20 + fi) * 10 + k] * ha[k];
        }
        float vr = br0_ - pr * LOG2E;
        float vz = bz0_ - pz * LOG2E;
        float r = __builtin_amdgcn_rcpf(1.f + __builtin_amdgcn_exp2f(vr));
        float z = __builtin_amdgcn_rcpf(1.f + __builtin_amdgcn_exp2f(vz));
        float y = bni0 + r * (ph * S2 + bh);
        float n = 1.f - 2.f * __builtin_amdgcn_rcpf(1.f + __builtin_amdgcn_exp2f(y));
        h = ok ? (n + z * (h - n)) : 0.f;
    }

    // ---- persistent priority asymmetry keyed on physical wave slot ----
    // HW_REG_HW_ID (id=4), offset 0, size 4 -> WAVE_ID[3:0]; imm = (3<<11)|4.
    {
        int p = __builtin_amdgcn_s_getreg(0x1804) & 3;
        if (p == 1)      __builtin_amdgcn_s_setprio(1);
        else if (p == 2) __builtin_amdgcn_s_setprio(2);
        else if (p == 3) __builtin_amdgcn_s_setprio(3);
    }

    // ---- prologue: stage h_1 and issue the first gather ----
    sHrow[f] = h;
    __builtin_amdgcn_wave_barrier();      // one-time (outside hot loop)
    v4f p0 = *(const v4f*)(sHrow);
    v4f p1 = *(const v4f*)(sHrow + 4);
    v2f p2 = *(const v2f*)(sHrow + 8);
    v4f r0, r1; v2f r2;

    // One iteration: gates from (a0,a1,a2) -> new h; write h; issue reads into
    // (n0,n1,n2); o-dot from the old (a0,a1,a2) + store fill the write->read
    // roundtrip window. NO in-loop fences: write/read alias through sHrow so
    // ordering is guaranteed; the scheduler is free to pack the window.
    #define STEP(a0, a1, a2, n0, n1, n2)                                        \
    {                                                                           \
        v2f h2_0 = __builtin_shufflevector(a0, a0, 0, 1);                       \
        v2f h2_1 = __builtin_shufflevector(a0, a0, 2, 3);                       \
        v2f h2_2 = __builtin_shufflevector(a1, a1, 0, 1);                       \
        v2f h2_3 = __builtin_shufflevector(a1, a1, 2, 3);                       \
        v2f h2_4 = a2;                                                          \
        v2f ar = wr0 * h2_0 + BR2;                                              \
        v2f az = wz0 * h2_0 + BZ2;                                              \
        v2f ai = wi0 * h2_0 + BI2;                                              \
        v2f ah = wh0 * h2_0 + BH2;                                              \
        ar += wr1 * h2_1; az += wz1 * h2_1; ai += wi1 * h2_1; ah += wh1 * h2_1; \
        ar += wr2 * h2_2; az += wz2 * h2_2; ai += wi2 * h2_2; ah += wh2 * h2_2; \
        ar += wr3 * h2_3; az += wz3 * h2_3; ai += wi3 * h2_3; ah += wh3 * h2_3; \
        ar += wr4 * h2_4; az += wz4 * h2_4; ai += wi4 * h2_4; ah += wh4 * h2_4; \
        float arx = ar.x + ar.y;                                                \
        float azx = az.x + az.y;                                                \
        float aix = ai.x + ai.y;                                                \
        float ahx = ah.x + ah.y;                                                \
        float er = __builtin_amdgcn_exp2f(arx);                                 \
        float rr = __builtin_amdgcn_rcpf(1.f + er);                             \
        float ez = __builtin_amdgcn_exp2f(azx);                                 \
        float y  = __builtin_fmaf(rr, ahx, aix);                                \
        float en = __builtin_amdgcn_exp2f(y);                                   \
        float pp = en * ez;                                                     \
        float u  = pp + (h - ez);                                               \
        float num = __builtin_fmaf(h, en, u);                                   \
        float den = (pp + (en + ez)) + 1.f;                                     \
        h = num * __builtin_amdgcn_rcpf(den);   /* padded lanes: h stays 0 */   \
        sHrow[f] = h;                                                           \
        n0 = *(const v4f*)(sHrow);                                              \
        n1 = *(const v4f*)(sHrow + 4);                                          \
        n2 = *(const v2f*)(sHrow + 8);                                          \
        /* o-dot from OLD gather regs: fills the roundtrip window */            \
        v2f ao = wo0 * h2_0 + BO2;                                              \
        ao += wo1 * h2_1;                                                       \
        ao += wo2 * h2_2;                                                       \
        ao += wo3 * h2_3;                                                       \
        ao += wo4 * h2_4;                                                       \
        float o = ao.x + ao.y;            /* = l1(h_t) = o_{t-1} */             \
        if (ok) pb[0] = o;                                                      \
        pb -= HID;                                                              \
    }

    // ---- t = 1 .. 510 (255 ping-pong pairs), then t = 511 peeled ----
    #pragma unroll 1
    for (int t = 1; t + 1 < STEPS; t += 2) {
        STEP(p0, p1, p2, r0, r1, r2);
        STEP(r0, r1, r2, p0, p1, p2);
    }
    STEP(p0, p1, p2, r0, r1, r2);       // t = 511; r now holds gather of h_512
    #undef STEP

    // ---- epilogue: o_511 = l1(h_512) at position 0 ----
    {
        v2f ao = wo0 * __builtin_shufflevector(r0, r0, 0, 1) + BO2;
        ao += wo1 * __builtin_shufflevector(r0, r0, 2, 3);
        ao += wo2 * __builtin_shufflevector(r1, r1, 0, 1);
        ao += wo3 * __builtin_shufflevector(r1, r1, 2, 3);
        ao += wo4 * r2;
        if (ok) pb[0] = ao.x + ao.y;
    }
}

extern "C" void kernel_launch(void* const* d_in, const int* in_sizes, int n_in,
                              void* d_out, int out_size, void* d_ws, size_t ws_size,
                              hipStream_t stream) {
    (void)in_sizes; (void)n_in; (void)d_ws; (void)ws_size; (void)out_size;
    dim3 grid(2048), block(64);   // 4 batches/wave, 2048 waves -> 2 waves per SIMD
    gru_decoder_kernel<<<grid, block, 0, stream>>>(
        (const float*)d_in[0], (const float*)d_in[1], (const float*)d_in[2],
        (const float*)d_in[3], (const float*)d_in[4], (const float*)d_in[5],
        (const float*)d_in[6], (const float*)d_in[7], (const float*)d_in[8],
        (float*)d_out);
}